// Round 1
// baseline (204.234 us; speedup 1.0000x reference)
//
#include <hip/hip_runtime.h>

// Problem constants (x = [B=64, C=133, H=64, W=64] fp32, K=2)
#define B_  64
#define CH  133
#define CM  128   // channels that get max-pooled
#define H_  64
#define W_  64
#define HO  32
#define WO  32

// One block per (b, ho): 32 windows (wo) x 133 channels.
// Thread layout: wo = tid & 31, channel-group g = tid >> 5 (8 groups).
// Each thread streams 16 pooled channels; argmax histogram packed into a u32
// (4 bytes, one per window position; max count 128 fits in 8 bits), merged
// via one LDS atomicAdd per thread. Stats phase done by lanes tid<32.
__global__ __launch_bounds__(256)
void pool_stats_kernel(const float* __restrict__ x, float* __restrict__ out) {
    const int ho = blockIdx.x;            // 0..31
    const int b  = blockIdx.y;            // 0..63
    const int wo = threadIdx.x & 31;
    const int g  = threadIdx.x >> 5;      // 0..7

    __shared__ unsigned int hist[WO];
    if (threadIdx.x < WO) hist[threadIdx.x] = 0u;
    __syncthreads();

    const float* xb = x + (size_t)b * CH * (H_ * W_);
    float*       ob = out + (size_t)b * CH * (HO * WO);

    const int r0off = (2 * ho) * W_ + 2 * wo;  // row 2*ho, col 2*wo
    const int r1off = r0off + W_;              // row 2*ho+1

    unsigned int packed = 0u;
    #pragma unroll 4
    for (int c = g; c < CM; c += 8) {
        const float* xc = xb + (size_t)c * (H_ * W_);
        const float2 r0 = *(const float2*)(xc + r0off);
        const float2 r1 = *(const float2*)(xc + r1off);
        // flatten order (kh,kw): v0=(0,0) v1=(0,1) v2=(1,0) v3=(1,1)
        float best = r0.x; int idx = 0;
        if (r0.y > best) { best = r0.y; idx = 1; }  // strict > = first-max, matches jnp.argmax
        if (r1.x > best) { best = r1.x; idx = 2; }
        if (r1.y > best) { best = r1.y; idx = 3; }
        ob[c * (HO * WO) + ho * WO + wo] = best;
        packed += 1u << (idx * 8);
    }
    atomicAdd(&hist[wo], packed);
    __syncthreads();

    if (threadIdx.x < WO) {
        const int wx = threadIdx.x;  // this lane's wo
        const unsigned int p = hist[wx];
        const float inv = 1.0f / 128.0f;
        const float w0 = (float)( p        & 0xFFu) * inv;
        const float w1 = (float)((p >> 8)  & 0xFFu) * inv;
        const float w2 = (float)((p >> 16) & 0xFFu) * inv;
        const float w3 = (float)((p >> 24) & 0xFFu) * inv;

        const int s0 = (2 * ho) * W_ + 2 * wx;
        const int s1 = s0 + W_;

        const float* cmu0 = xb + (size_t)(CM + 0) * (H_ * W_);
        const float* cmu1 = xb + (size_t)(CM + 1) * (H_ * W_);
        const float* cv0  = xb + (size_t)(CM + 2) * (H_ * W_);
        const float* cv1  = xb + (size_t)(CM + 3) * (H_ * W_);
        const float* ccv  = xb + (size_t)(CM + 4) * (H_ * W_);

        const float2 a0 = *(const float2*)(cmu0 + s0);
        const float2 a1 = *(const float2*)(cmu0 + s1);
        const float2 b0 = *(const float2*)(cmu1 + s0);
        const float2 b1 = *(const float2*)(cmu1 + s1);
        const float2 va = *(const float2*)(cv0 + s0);
        const float2 vb = *(const float2*)(cv0 + s1);
        const float2 vc = *(const float2*)(cv1 + s0);
        const float2 vd = *(const float2*)(cv1 + s1);
        const float2 ca = *(const float2*)(ccv + s0);
        const float2 cb = *(const float2*)(ccv + s1);

        const float mean0 = w0 * a0.x + w1 * a0.y + w2 * a1.x + w3 * a1.y;
        const float mean1 = w0 * b0.x + w1 * b0.y + w2 * b1.x + w3 * b1.y;

        const float var1a = w0 * va.x + w1 * va.y + w2 * vb.x + w3 * vb.y;
        const float var1b = w0 * vc.x + w1 * vc.y + w2 * vd.x + w3 * vd.y;
        const float cov1  = w0 * ca.x + w1 * ca.y + w2 * cb.x + w3 * cb.y;

        const float d00 = a0.x - mean0, d01 = a0.y - mean0,
                    d02 = a1.x - mean0, d03 = a1.y - mean0;
        const float e00 = b0.x - mean1, e01 = b0.y - mean1,
                    e02 = b1.x - mean1, e03 = b1.y - mean1;

        const float var2a = w0 * d00 * d00 + w1 * d01 * d01 + w2 * d02 * d02 + w3 * d03 * d03;
        const float var2b = w0 * e00 * e00 + w1 * e01 * e01 + w2 * e02 * e02 + w3 * e03 * e03;
        const float cov2  = w0 * d00 * e00 + w1 * d01 * e01 + w2 * d02 * e02 + w3 * d03 * e03;

        const int base = ho * WO + wx;
        ob[(CM + 0) * (HO * WO) + base] = mean0;
        ob[(CM + 1) * (HO * WO) + base] = mean1;
        ob[(CM + 2) * (HO * WO) + base] = var1a + var2a;
        ob[(CM + 3) * (HO * WO) + base] = var1b + var2b;
        ob[(CM + 4) * (HO * WO) + base] = cov1 + cov2;
    }
}

extern "C" void kernel_launch(void* const* d_in, const int* in_sizes, int n_in,
                              void* d_out, int out_size, void* d_ws, size_t ws_size,
                              hipStream_t stream) {
    const float* x = (const float*)d_in[0];
    float* out = (float*)d_out;
    dim3 grid(HO, B_);   // 32 x 64 = 2048 blocks
    dim3 block(256);
    pool_stats_kernel<<<grid, block, 0, stream>>>(x, out);
}

// Round 2
// 201.674 us; speedup vs baseline: 1.0127x; 1.0127x over previous
//
#include <hip/hip_runtime.h>

// Problem constants (x = [B=64, C=133, H=64, W=64] fp32, K=2)
#define B_  64
#define CH  133
#define CM  128   // channels that get max-pooled
#define H_  64
#define W_  64
#define HO  32
#define WO  32

// One block per (b, ho). Thread layout: window-pair p = tid & 15 (covers
// wo = 2p, 2p+1), channel-group g = tid >> 4 (16 groups, 8 channels each).
// Each channel iteration: two float4 loads (rows 2ho, 2ho+1; 16 B/lane,
// 16 lanes cover a full 64-float row) feed TWO 2x2 windows; pooled outputs
// stored as one float2 (contiguous wo pair). Argmax histogram byte-packed
// into u32 (count <= 128 fits in 8 bits), merged via 2 LDS atomicAdds per
// thread. Stats channels (5) handled by lanes tid<32 after the barrier.
__global__ __launch_bounds__(256)
void pool_stats_kernel(const float* __restrict__ x, float* __restrict__ out) {
    const int ho = blockIdx.x;            // 0..31
    const int b  = blockIdx.y;            // 0..63
    const int p  = threadIdx.x & 15;      // window pair -> wo = 2p, 2p+1
    const int g  = threadIdx.x >> 4;      // 0..15

    __shared__ unsigned int hist[WO];
    if (threadIdx.x < WO) hist[threadIdx.x] = 0u;
    __syncthreads();

    const float* xb = x + (size_t)b * CH * (H_ * W_);
    float*       ob = out + (size_t)b * CH * (HO * WO);

    const int r0off = (2 * ho) * W_ + 4 * p;   // row 2*ho, col 4p (16B aligned)
    const int r1off = r0off + W_;              // row 2*ho+1

    unsigned int packedA = 0u, packedB = 0u;
    #pragma unroll 4
    for (int c = g; c < CM; c += 16) {
        const float* xc = xb + (size_t)c * (H_ * W_);
        const float4 r0 = *(const float4*)(xc + r0off);
        const float4 r1 = *(const float4*)(xc + r1off);
        // window A: (r0.x r0.y / r1.x r1.y), window B: (r0.z r0.w / r1.z r1.w)
        // flatten order (kh,kw): 0=(0,0) 1=(0,1) 2=(1,0) 3=(1,1)
        float bestA = r0.x; int idxA = 0;
        if (r0.y > bestA) { bestA = r0.y; idxA = 1; }  // strict > = first-max (jnp.argmax)
        if (r1.x > bestA) { bestA = r1.x; idxA = 2; }
        if (r1.y > bestA) { bestA = r1.y; idxA = 3; }
        float bestB = r0.z; int idxB = 0;
        if (r0.w > bestB) { bestB = r0.w; idxB = 1; }
        if (r1.z > bestB) { bestB = r1.z; idxB = 2; }
        if (r1.w > bestB) { bestB = r1.w; idxB = 3; }
        float2 st; st.x = bestA; st.y = bestB;
        *(float2*)(ob + c * (HO * WO) + ho * WO + 2 * p) = st;
        packedA += 1u << (idxA * 8);
        packedB += 1u << (idxB * 8);
    }
    atomicAdd(&hist[2 * p],     packedA);
    atomicAdd(&hist[2 * p + 1], packedB);
    __syncthreads();

    if (threadIdx.x < WO) {
        const int wx = threadIdx.x;  // this lane's wo
        const unsigned int pk = hist[wx];
        const float inv = 1.0f / 128.0f;
        const float w0 = (float)( pk        & 0xFFu) * inv;
        const float w1 = (float)((pk >> 8)  & 0xFFu) * inv;
        const float w2 = (float)((pk >> 16) & 0xFFu) * inv;
        const float w3 = (float)((pk >> 24) & 0xFFu) * inv;

        const int s0 = (2 * ho) * W_ + 2 * wx;
        const int s1 = s0 + W_;

        const float* cmu0 = xb + (size_t)(CM + 0) * (H_ * W_);
        const float* cmu1 = xb + (size_t)(CM + 1) * (H_ * W_);
        const float* cv0  = xb + (size_t)(CM + 2) * (H_ * W_);
        const float* cv1  = xb + (size_t)(CM + 3) * (H_ * W_);
        const float* ccv  = xb + (size_t)(CM + 4) * (H_ * W_);

        const float2 a0 = *(const float2*)(cmu0 + s0);
        const float2 a1 = *(const float2*)(cmu0 + s1);
        const float2 b0 = *(const float2*)(cmu1 + s0);
        const float2 b1 = *(const float2*)(cmu1 + s1);
        const float2 va = *(const float2*)(cv0 + s0);
        const float2 vb = *(const float2*)(cv0 + s1);
        const float2 vc = *(const float2*)(cv1 + s0);
        const float2 vd = *(const float2*)(cv1 + s1);
        const float2 ca = *(const float2*)(ccv + s0);
        const float2 cb = *(const float2*)(ccv + s1);

        const float mean0 = w0 * a0.x + w1 * a0.y + w2 * a1.x + w3 * a1.y;
        const float mean1 = w0 * b0.x + w1 * b0.y + w2 * b1.x + w3 * b1.y;

        const float var1a = w0 * va.x + w1 * va.y + w2 * vb.x + w3 * vb.y;
        const float var1b = w0 * vc.x + w1 * vc.y + w2 * vd.x + w3 * vd.y;
        const float cov1  = w0 * ca.x + w1 * ca.y + w2 * cb.x + w3 * cb.y;

        const float d00 = a0.x - mean0, d01 = a0.y - mean0,
                    d02 = a1.x - mean0, d03 = a1.y - mean0;
        const float e00 = b0.x - mean1, e01 = b0.y - mean1,
                    e02 = b1.x - mean1, e03 = b1.y - mean1;

        const float var2a = w0 * d00 * d00 + w1 * d01 * d01 + w2 * d02 * d02 + w3 * d03 * d03;
        const float var2b = w0 * e00 * e00 + w1 * e01 * e01 + w2 * e02 * e02 + w3 * e03 * e03;
        const float cov2  = w0 * d00 * e00 + w1 * d01 * e01 + w2 * d02 * e02 + w3 * d03 * e03;

        const int base = ho * WO + wx;
        ob[(CM + 0) * (HO * WO) + base] = mean0;
        ob[(CM + 1) * (HO * WO) + base] = mean1;
        ob[(CM + 2) * (HO * WO) + base] = var1a + var2a;
        ob[(CM + 3) * (HO * WO) + base] = var1b + var2b;
        ob[(CM + 4) * (HO * WO) + base] = cov1 + cov2;
    }
}

extern "C" void kernel_launch(void* const* d_in, const int* in_sizes, int n_in,
                              void* d_out, int out_size, void* d_ws, size_t ws_size,
                              hipStream_t stream) {
    const float* x = (const float*)d_in[0];
    float* out = (float*)d_out;
    dim3 grid(HO, B_);   // 32 x 64 = 2048 blocks
    dim3 block(256);
    pool_stats_kernel<<<grid, block, 0, stream>>>(x, out);
}